// Round 12
// baseline (615.742 us; speedup 1.0000x reference)
//
#include <hip/hip_runtime.h>

// GraphFilterRNN: u = lsigf(W_D, S, relu(lsigf(W_A,S,x,bA)+lsigf(W_B,S,h,bB)), bD)
// Horner form: per path, u = ((w3 S + w2) S + w1) S + w0,  w_k = A_k x + B_k h.
// B=16, N=1024, E=1, K=4, feature dims all 128.
//
// Round 12: round-11 bodies (proven 103.5us) fused into ONE plain-launch
// megakernel with a software grid barrier (atomics + threadfence — the
// grid.sync() mechanism without the cooperative-launch API that failed graph
// capture in round 10). 512 blocks x 256 thr, launch_bounds(256,3), 48KB LDS
// -> >=3 blocks/CU resident capacity 768 >= 512 (deadlock-safe). Barrier
// slots zeroed per call via hipMemsetAsync (deterministic under replay).

typedef __attribute__((ext_vector_type(8))) short short8;
typedef __attribute__((ext_vector_type(4))) float floatx4;

#define AS1 __attribute__((address_space(1)))
#define AS3 __attribute__((address_space(3)))

__device__ __forceinline__ unsigned short f2bf(float f) {
  union { float f; unsigned u; } v; v.f = f;
  unsigned r = v.u + 0x7fffu + ((v.u >> 16) & 1u);
  return (unsigned short)(r >> 16);
}
__device__ __forceinline__ float bf2f(unsigned short b) {
  union { unsigned u; float f; } v; v.u = ((unsigned)b) << 16;
  return v.f;
}

__device__ __forceinline__ void gload16(const void* g, void* l) {
  __builtin_amdgcn_global_load_lds((const AS1 void*)g, (AS3 void*)l, 16, 0, 0);
}

// ---------------------------------------------------------------------------
// Software grid barrier. bar layout: slot idx -> cnt at [idx*64], flag at
// [idx*64+16] (256B separation). All 512 blocks co-resident by capacity.
// ---------------------------------------------------------------------------
__device__ __forceinline__ void gbar(unsigned* bar, int idx) {
  __syncthreads();
  if (threadIdx.x == 0) {
    __threadfence();                                   // release prior stores
    unsigned* cnt  = bar + idx * 64;
    unsigned* flag = bar + idx * 64 + 16;
    if (atomicAdd(cnt, 1u) == 511u) {
      atomicExch(flag, 1u);                            // last arrival releases
    } else {
      while (atomicAdd(flag, 0u) == 0u)
        __builtin_amdgcn_s_sleep(2);
    }
    __threadfence();                                   // acquire
  }
  __syncthreads();
}

// ---------------------------------------------------------------------------
// GEMM phase body (round-11 proven): C[m,n] = sum_k A[m,k]*Bt[n,k] (+cinit).
// Tile 64x64, BK=64, 4 waves, wave-tile 32x32. LDS: 3 slots of 128x64
// (A rows 0..63, B rows 64..127), XOR-swizzle via pre-swizzled source.
// 2-deep prefetch; per K-step: vmcnt(4) (0 at last), s_barrier,
// stage((t+2)%3), ds_read + setprio MFMA. Exits with vmcnt==0.
// EPI 0: bf16 out (+ci); 2: f32 out (+ci); 3: mix (chunk dest, +bias kc0);
// EPI 4: relu(+ci) -> LDS transpose -> node-major bf16 (h_next^T).
// wg: virtual block id; XCD batch-cluster swizzle (xcd = wg&7).
// ---------------------------------------------------------------------------
template<int EPI, int KK>
__device__ __forceinline__ void gemm_body(
    const int wg, unsigned short (*buf)[128 * 64],
    const unsigned short* __restrict__ A, long long aBatch, int lda,
    const unsigned short* __restrict__ Bt, long long bBatch, int ldb,
    const unsigned short* __restrict__ cinit, long long ciBatch,
    const float* __restrict__ bias,
    unsigned short* __restrict__ outb, long long obBatch,
    float* __restrict__ outf,
    unsigned short* __restrict__ mixv, long long mvBatch)
{
  constexpr int NT   = KK / 64;
  constexpr int MT   = (EPI == 3) ? 8 : 2;   // m-tiles (M=512 mixes, else 128)
  constexpr int PERB = 16 * MT;              // virtual blocks per batch

  const int xcd = wg & 7;
  const int idx = wg >> 3;
  const int b   = xcd * 2 + idx / PERB;
  const int r   = idx % PERB;
  const int n0  = (r & 15) * 64;
  const int m0  = (r >> 4) * 64;

  const int tid  = threadIdx.x;
  const int wave = tid >> 6;
  const int lane = tid & 63;
  const int wr   = (wave >> 1) * 32;
  const int wc   = (wave & 1) * 32;
  const int l15  = lane & 15;
  const int lhi  = lane >> 4;

  const unsigned short* Ab = A + (long long)b * aBatch;
  const unsigned short* Bb = Bt + (long long)b * bBatch;

  const unsigned short* src[4];
  int ldsoff[4];
  #pragma unroll
  for (int i = 0; i < 4; ++i) {
    const int u  = wave * 4 + i;
    const int q  = u * 64 + lane;
    const int rr = q >> 3;
    const int c8 = ((q & 7) ^ (rr & 7)) * 8;
    src[i] = (rr < 64) ? Ab + (long long)(m0 + rr) * lda + c8
                       : Bb + (long long)(n0 + rr - 64) * ldb + c8;
    ldsoff[i] = u * 512;
  }
  auto stage = [&](int slot) {
    #pragma unroll
    for (int i = 0; i < 4; ++i) {
      gload16(src[i], &buf[slot][ldsoff[i]]);
      src[i] += 64;
    }
  };

  int aoff[2][2], boff[2][2];
  #pragma unroll
  for (int kk = 0; kk < 2; ++kk) {
    #pragma unroll
    for (int mi = 0; mi < 2; ++mi) {
      const int rowa = wr + mi * 16 + l15;
      aoff[kk][mi] = rowa * 64 + (((kk * 4 + lhi) ^ (rowa & 7)) << 3);
    }
    #pragma unroll
    for (int ni = 0; ni < 2; ++ni) {
      const int rowb = 64 + wc + ni * 16 + l15;
      boff[kk][ni] = rowb * 64 + (((kk * 4 + lhi) ^ (rowb & 7)) << 3);
    }
  }

  floatx4 acc[2][2];
  #pragma unroll
  for (int mi = 0; mi < 2; ++mi)
    #pragma unroll
    for (int ni = 0; ni < 2; ++ni)
      acc[mi][ni] = (floatx4){0.f, 0.f, 0.f, 0.f};

  stage(0);
  if (NT > 1) stage(1);

  #pragma unroll
  for (int t = 0; t < NT; ++t) {
    if (t + 1 < NT) { asm volatile("s_waitcnt vmcnt(4)" ::: "memory"); }
    else            { asm volatile("s_waitcnt vmcnt(0)" ::: "memory"); }
    __builtin_amdgcn_s_barrier();          // all waves' tile-t loads landed;
    __builtin_amdgcn_sched_barrier(0);     // all tile-(t-1) reads consumed
    if (t + 2 < NT) stage((t + 2) % 3);    // overwrites slot (t-1)%3

    const unsigned short* bp = &buf[t % 3][0];
    #pragma unroll
    for (int kk = 0; kk < 2; ++kk) {
      short8 af[2], bv[2];
      #pragma unroll
      for (int mi = 0; mi < 2; ++mi) af[mi] = *(const short8*)(bp + aoff[kk][mi]);
      #pragma unroll
      for (int ni = 0; ni < 2; ++ni) bv[ni] = *(const short8*)(bp + boff[kk][ni]);
      __builtin_amdgcn_s_setprio(1);
      #pragma unroll
      for (int mi = 0; mi < 2; ++mi)
        #pragma unroll
        for (int ni = 0; ni < 2; ++ni)
          acc[mi][ni] = __builtin_amdgcn_mfma_f32_16x16x32_bf16(af[mi], bv[ni], acc[mi][ni], 0, 0, 0);
      __builtin_amdgcn_s_setprio(0);
    }
  }
  // loop exit: vmcnt == 0.

  if (EPI == 0) {
    const unsigned short* ci = cinit + (long long)b * ciBatch;
    unsigned short* ob = outb + (long long)b * obBatch;
    #pragma unroll
    for (int mi = 0; mi < 2; ++mi)
      #pragma unroll
      for (int ni = 0; ni < 2; ++ni)
        #pragma unroll
        for (int j = 0; j < 4; ++j) {
          const int row = m0 + wr + mi * 16 + lhi * 4 + j;
          const int col = n0 + wc + ni * 16 + l15;
          ob[(long long)row * 1024 + col] =
              f2bf(acc[mi][ni][j] + bf2f(ci[(long long)row * 1024 + col]));
        }
  } else if (EPI == 2) {
    const unsigned short* ci = cinit + (long long)b * ciBatch;
    float* of = outf + (long long)b * (128 * 1024);
    #pragma unroll
    for (int mi = 0; mi < 2; ++mi)
      #pragma unroll
      for (int ni = 0; ni < 2; ++ni)
        #pragma unroll
        for (int j = 0; j < 4; ++j) {
          const int row = m0 + wr + mi * 16 + lhi * 4 + j;
          const int col = n0 + wc + ni * 16 + l15;
          of[(long long)row * 1024 + col] =
              acc[mi][ni][j] + bf2f(ci[(long long)row * 1024 + col]);
        }
  } else if (EPI == 3) {  // mix: logical M=512; chunk kc = row>>7
    #pragma unroll
    for (int mi = 0; mi < 2; ++mi)
      #pragma unroll
      for (int ni = 0; ni < 2; ++ni)
        #pragma unroll
        for (int j = 0; j < 4; ++j) {
          const int gr = m0 + wr + mi * 16 + lhi * 4 + j;   // 0..511
          const int kc = gr >> 7;
          const int rl = gr & 127;
          const int col = n0 + wc + ni * 16 + l15;
          unsigned short* dst = (kc == 3) ? (mixv + (long long)b * mvBatch)
                                          : (outb + (long long)b * obBatch + kc * (128 * 1024));
          float v = acc[mi][ni][j];
          if (kc == 0 && bias != nullptr) v += bias[rl];
          dst[(long long)rl * 1024 + col] = f2bf(v);
        }
  } else {  // EPI == 4: relu(+ci) -> transpose in LDS -> hnt[node][128]
    const unsigned short* ci = cinit + (long long)b * ciBatch;
    __syncthreads();   // vmcnt==0; all LDS reads consumed
    unsigned short (*tt)[72] = (unsigned short(*)[72])(&buf[0][0]);
    #pragma unroll
    for (int mi = 0; mi < 2; ++mi)
      #pragma unroll
      for (int ni = 0; ni < 2; ++ni)
        #pragma unroll
        for (int j = 0; j < 4; ++j) {
          const int rowl = wr + mi * 16 + lhi * 4 + j;      // local feat 0..63
          const int coll = wc + ni * 16 + l15;              // local node 0..63
          float v = acc[mi][ni][j] +
                    bf2f(ci[(long long)(m0 + rowl) * 1024 + n0 + coll]);
          tt[coll][rowl] = f2bf(fmaxf(v, 0.f));
        }
    __syncthreads();
    unsigned short* ob = outb + (long long)b * obBatch;     // hnt, stride 128
    #pragma unroll
    for (int i = 0; i < 2; ++i) {
      const int flat = tid + i * 256;     // 0..511 = 64 nodes x 8 segs
      const int node = flat >> 3;
      const int seg  = flat & 7;
      *(short8*)(&ob[(long long)(n0 + node) * 128 + m0 + seg * 8]) =
          *(const short8*)(&tt[node][seg * 8]);
    }
  }
}

// ---------------------------------------------------------------------------
// prep phase body (round-11 proven prep_all).
// ---------------------------------------------------------------------------
__device__ __forceinline__ void prep_body(
    const int wg, unsigned short (*buf)[128 * 64],
    const float* __restrict__ x, const float* __restrict__ hid,
    const float* __restrict__ S,
    const float* __restrict__ wA, const float* __restrict__ wB,
    const float* __restrict__ wD,
    const float* __restrict__ bA, const float* __restrict__ bB,
    unsigned short* __restrict__ St, unsigned short* __restrict__ z0t,
    unsigned short* __restrict__ W1, unsigned short* __restrict__ W2,
    float* __restrict__ biasAB)
{
  float (*t)[65] = (float(*)[65])(&buf[0][0]);   // 16.6 KB scratch in 48KB
  const int tid = threadIdx.x;

  #pragma unroll
  for (int k = 0; k < 2; ++k) {
    const int i = wg * 512 + k * 256 + tid;
    if (i < 512 * 256) {
      const int row = i >> 8, g2 = i & 255;
      const int kk = row >> 7, h = row & 127;
      const float v = (g2 < 128) ? wA[(h * 4 + kk) * 128 + g2]
                                 : wB[(h * 4 + kk) * 128 + (g2 - 128)];
      W1[i] = f2bf(v);
    } else if (i < 512 * 256 + 512 * 128) {
      const int j = i - 512 * 256;
      const int row = j >> 7, h2 = j & 127;
      const int kk = row >> 7, f = row & 127;
      W2[j] = f2bf(wD[(f * 4 + kk) * 128 + h2]);
    } else if (i < 512 * 256 + 512 * 128 + 128) {
      const int l = i - 512 * 256 - 512 * 128;
      biasAB[l] = bA[l] + bB[l];
    }
  }

  const int b  = (wg & 7) * 2 + (wg >> 3) / 32;
  const int jj = (wg >> 3) % 32;       // 0..31 within batch
  const int tx = tid & 63;
  const int ty = tid >> 6;             // 0..3

  const float* Sb = S + (long long)b * (1024 * 1024);
  unsigned short* Stb = St + (long long)b * (1024 * 1024);
  for (int q = 0; q < 8; ++q) {
    const int tile = jj * 8 + q;               // 0..255
    const int c0 = (tile & 15) * 64, r0 = (tile >> 4) * 64;
    __syncthreads();
    #pragma unroll
    for (int i = 0; i < 64; i += 4)
      t[ty + i][tx] = Sb[(long long)(r0 + ty + i) * 1024 + c0 + tx];
    __syncthreads();
    #pragma unroll
    for (int i = 0; i < 64; i += 4)
      Stb[(long long)(c0 + ty + i) * 1024 + r0 + tx] = f2bf(t[tx][ty + i]);
  }

  unsigned short* zb = z0t + (long long)b * (1024 * 256);
  for (int q = 0; q < 2; ++q) {
    const int idx2 = jj * 2 + q;               // 0..63
    const int srch = idx2 >> 5;                // 0: x, 1: hidden
    const int t2   = idx2 & 31;
    const int c0 = (t2 & 15) * 64, r0 = ((t2 >> 4) & 1) * 64;
    const float* sp = (srch ? hid : x) + (long long)b * (128 * 1024);
    __syncthreads();
    #pragma unroll
    for (int i = 0; i < 64; i += 4)
      t[ty + i][tx] = sp[(long long)(r0 + ty + i) * 1024 + c0 + tx];
    __syncthreads();
    #pragma unroll
    for (int i = 0; i < 64; i += 4)
      zb[(long long)(c0 + ty + i) * 256 + srch * 128 + r0 + tx] = f2bf(t[tx][ty + i]);
  }
}

// ---------------------------------------------------------------------------
// Megakernel: 512 blocks x 256 threads, plain launch, 9 phases, 8 sw grid
// barriers. Mix phases loop 4 virtual tiles (wgid = it*512+wg keeps wgid&7
// == wg&7 -> XCD/batch pinning holds). __syncthreads() between virtual-tile
// iterations guards the slot-0 restage vs last-K-step LDS reads.
// ---------------------------------------------------------------------------
__global__ __launch_bounds__(256, 3)
void mega(const float* x, const float* hid, const float* S,
          const float* wA, const float* wB, const float* wD,
          const float* bA, const float* bB, const float* bD,
          unsigned short* St, unsigned short* z0t, unsigned short* cini,
          unsigned short* vb0, unsigned short* vb1, unsigned short* hnt,
          unsigned short* W1, unsigned short* W2, float* bAB, float* out,
          unsigned* bar)
{
  __shared__ unsigned short buf[3][128 * 64];
  const int wg = blockIdx.x;

  const long long NB  = 128 * 1024;
  const long long NB2 = 1024 * 128;
  const long long CI  = 3 * NB;
  const long long SB  = 1024 * 1024;

  // phase 1: prep (weights, S^T, [x;h]^T)
  prep_body(wg, buf, x, hid, S, wA, wB, wD, bA, bB, St, z0t, W1, W2, bAB);
  gbar(bar, 0);

  // phase 2: mix1  w_k = [A_k|B_k] @ [x;h]  (4 virtual tiles/block)
  #pragma unroll 1
  for (int it = 0; it < 4; ++it) {
    gemm_body<3, 256>(it * 512 + wg, buf, W1, 0, 256, z0t, 1024 * 256, 256,
                      nullptr, 0, bAB, cini, CI, nullptr, vb0, NB);
    __syncthreads();
  }
  gbar(bar, 1);

  // phases 3-5: Horner part 1; h_next^T via EPI4
  gemm_body<0, 1024>(wg, buf, vb0, NB, 1024, St, SB, 1024,
                     cini + 2 * NB, CI, nullptr, vb1, NB, nullptr, nullptr, 0);
  gbar(bar, 2);
  gemm_body<0, 1024>(wg, buf, vb1, NB, 1024, St, SB, 1024,
                     cini + 1 * NB, CI, nullptr, vb0, NB, nullptr, nullptr, 0);
  gbar(bar, 3);
  gemm_body<4, 1024>(wg, buf, vb0, NB, 1024, St, SB, 1024,
                     cini, CI, nullptr, hnt, NB2, nullptr, nullptr, 0);
  gbar(bar, 4);

  // phase 6: mix2  d_k = D_k @ h_next
  #pragma unroll 1
  for (int it = 0; it < 4; ++it) {
    gemm_body<3, 128>(it * 512 + wg, buf, W2, 0, 128, hnt, NB2, 128,
                      nullptr, 0, bD, cini, CI, nullptr, vb0, NB);
    __syncthreads();
  }
  gbar(bar, 5);

  // phases 7-9: Horner part 2; f32 out via EPI2
  gemm_body<0, 1024>(wg, buf, vb0, NB, 1024, St, SB, 1024,
                     cini + 2 * NB, CI, nullptr, vb1, NB, nullptr, nullptr, 0);
  gbar(bar, 6);
  gemm_body<0, 1024>(wg, buf, vb1, NB, 1024, St, SB, 1024,
                     cini + 1 * NB, CI, nullptr, vb0, NB, nullptr, nullptr, 0);
  gbar(bar, 7);
  gemm_body<2, 1024>(wg, buf, vb0, NB, 1024, St, SB, 1024,
                     cini, CI, nullptr, nullptr, 0, out, nullptr, 0);
}

// ---------------------------------------------------------------------------
extern "C" void kernel_launch(void* const* d_in, const int* in_sizes, int n_in,
                              void* d_out, int out_size, void* d_ws, size_t ws_size,
                              hipStream_t stream)
{
  const float* x   = (const float*)d_in[0];
  const float* hid = (const float*)d_in[1];
  const float* S   = (const float*)d_in[2];
  const float* wA  = (const float*)d_in[3];
  const float* wB  = (const float*)d_in[4];
  const float* wD  = (const float*)d_in[5];
  const float* bA  = (const float*)d_in[6];
  const float* bB  = (const float*)d_in[7];
  const float* bD  = (const float*)d_in[8];
  float* out = (float*)d_out;

  char* ws = (char*)d_ws;
  auto alloc = [&](size_t bytes) {
    char* p = ws;
    ws += (bytes + 255) & ~(size_t)255;
    return p;
  };
  unsigned short* St   = (unsigned short*)alloc(16ull * 1024 * 1024 * 2); // S^T bf16
  unsigned short* z0t  = (unsigned short*)alloc(16ull * 1024 * 256 * 2);  // [x;h]^T bf16
  unsigned short* cini = (unsigned short*)alloc(16ull * 3 * 128 * 1024 * 2);
  unsigned short* vb0  = (unsigned short*)alloc(16ull * 128 * 1024 * 2);
  unsigned short* vb1  = (unsigned short*)alloc(16ull * 128 * 1024 * 2);
  unsigned short* hnt  = (unsigned short*)alloc(16ull * 1024 * 128 * 2);  // h_next^T
  unsigned short* W1   = (unsigned short*)alloc(512 * 256 * 2);
  unsigned short* W2   = (unsigned short*)alloc(512 * 128 * 2);
  float*          bAB  = (float*)alloc(128 * 4);
  unsigned*       bar  = (unsigned*)alloc(8 * 64 * 4);   // 8 barrier slots

  hipMemsetAsync(bar, 0, 8 * 64 * 4, stream);
  mega<<<dim3(512), dim3(256), 0, stream>>>(
      x, hid, S, wA, wB, wD, bA, bB, bD,
      St, z0t, cini, vb0, vb1, hnt, W1, W2, bAB, out, bar);
}

// Round 13
// 103.255 us; speedup vs baseline: 5.9633x; 5.9633x over previous
//
#include <hip/hip_runtime.h>

// GraphFilterRNN: u = lsigf(W_D, S, relu(lsigf(W_A,S,x,bA)+lsigf(W_B,S,h,bB)), bD)
// Horner form: per path, u = ((w3 S + w2) S + w1) S + w0,  w_k = A_k x + B_k h.
// B=16, N=1024, E=1, K=4, feature dims all 128.
//
// Round 13 = round-11 verbatim (proven 103.5us): 9-kernel chain, GEMMs at
// 3 LDS slots / 2-deep prefetch / 3 blocks/CU (48KB, launch_bounds(256,3)),
// counted vmcnt(4/0), XOR-swizzled LDS via pre-swizzled source, setprio MFMA,
// XCD batch-cluster swizzle, fused prep_all, EPI4 fused h_next transpose.
// Megakernel routes (cooperative API + sw grid barrier) both condemned by
// rounds 10/12; launch-edge cost (~16us) has no viable mechanism here.

typedef __attribute__((ext_vector_type(8))) short short8;
typedef __attribute__((ext_vector_type(4))) float floatx4;

#define AS1 __attribute__((address_space(1)))
#define AS3 __attribute__((address_space(3)))

__device__ __forceinline__ unsigned short f2bf(float f) {
  union { float f; unsigned u; } v; v.f = f;
  unsigned r = v.u + 0x7fffu + ((v.u >> 16) & 1u);
  return (unsigned short)(r >> 16);
}
__device__ __forceinline__ float bf2f(unsigned short b) {
  union { unsigned u; float f; } v; v.u = ((unsigned)b) << 16;
  return v.f;
}

__device__ __forceinline__ void gload16(const void* g, void* l) {
  __builtin_amdgcn_global_load_lds((const AS1 void*)g, (AS3 void*)l, 16, 0, 0);
}

// ---------------------------------------------------------------------------
// GEMM: C[m,n] = sum_k A[m,k]*Bt[n,k] (+cinit in epilogue).
// Tile 64x64, BK=64, 4 waves, wave-tile 32x32 (2x2 acc).
// LDS: 3 slots of 128 rows x 64 k (A rows 0..63, B rows 64..127), XOR-swizzle
// via pre-swizzled global source + swizzled ds_read (linear gload_lds dest).
// Pipeline: 2-deep prefetch; per K-step: vmcnt(4) counted wait (0 at last),
// raw s_barrier, stage((t+2)%3), ds_read + setprio-wrapped MFMA.
// EPI 0: bf16 out (+ci); 2: f32 out (+ci); 3: mix (chunk dest, +bias kc0);
// EPI 4: relu(+ci) -> LDS transpose -> node-major bf16 (h_next^T).
// Grid: 1-D; XCD batch-cluster swizzle (bijective; 2 batches/XCD).
// ---------------------------------------------------------------------------
template<int EPI, int KK>
__global__ __launch_bounds__(256, 3)
void gemm_bt(const unsigned short* __restrict__ A, long long aBatch, int lda,
             const unsigned short* __restrict__ Bt, long long bBatch, int ldb,
             const unsigned short* __restrict__ cinit, long long ciBatch,
             const float* __restrict__ bias,
             unsigned short* __restrict__ outb, long long obBatch,
             float* __restrict__ outf, long long ofBatch,
             unsigned short* __restrict__ mixv, long long mvBatch)
{
  constexpr int NT   = KK / 64;
  constexpr int MT   = (EPI == 3) ? 8 : 2;   // m-tiles (M=512 mixes, else 128)
  constexpr int PERB = 16 * MT;              // blocks per batch
  __shared__ unsigned short buf[3][128 * 64];

  // XCD batch-cluster swizzle (bijective; 2 batches per XCD)
  const int wg  = blockIdx.x;
  const int xcd = wg & 7;
  const int idx = wg >> 3;
  const int b   = xcd * 2 + idx / PERB;
  const int r   = idx % PERB;
  const int n0  = (r & 15) * 64;
  const int m0  = (r >> 4) * 64;

  const int tid  = threadIdx.x;
  const int wave = tid >> 6;
  const int lane = tid & 63;
  const int wr   = (wave >> 1) * 32;
  const int wc   = (wave & 1) * 32;
  const int l15  = lane & 15;
  const int lhi  = lane >> 4;

  const unsigned short* Ab = A + (long long)b * aBatch;
  const unsigned short* Bb = Bt + (long long)b * bBatch;

  // per-thread staging sources (advance by 64 elems per staged tile)
  const unsigned short* src[4];
  int ldsoff[4];
  #pragma unroll
  for (int i = 0; i < 4; ++i) {
    const int u  = wave * 4 + i;                // 0..15
    const int q  = u * 64 + lane;               // 0..1023
    const int rr = q >> 3;                      // combined row 0..127
    const int c8 = ((q & 7) ^ (rr & 7)) * 8;    // inverse-swizzled k col
    src[i] = (rr < 64) ? Ab + (long long)(m0 + rr) * lda + c8
                       : Bb + (long long)(n0 + rr - 64) * ldb + c8;
    ldsoff[i] = u * 512;
  }
  auto stage = [&](int slot) {
    #pragma unroll
    for (int i = 0; i < 4; ++i) {
      gload16(src[i], &buf[slot][ldsoff[i]]);
      src[i] += 64;
    }
  };

  // per-thread LDS read offsets (within a slot)
  int aoff[2][2], boff[2][2];
  #pragma unroll
  for (int kk = 0; kk < 2; ++kk) {
    #pragma unroll
    for (int mi = 0; mi < 2; ++mi) {
      const int rowa = wr + mi * 16 + l15;
      aoff[kk][mi] = rowa * 64 + (((kk * 4 + lhi) ^ (rowa & 7)) << 3);
    }
    #pragma unroll
    for (int ni = 0; ni < 2; ++ni) {
      const int rowb = 64 + wc + ni * 16 + l15;
      boff[kk][ni] = rowb * 64 + (((kk * 4 + lhi) ^ (rowb & 7)) << 3);
    }
  }

  floatx4 acc[2][2];
  #pragma unroll
  for (int mi = 0; mi < 2; ++mi)
    #pragma unroll
    for (int ni = 0; ni < 2; ++ni)
      acc[mi][ni] = (floatx4){0.f, 0.f, 0.f, 0.f};

  stage(0);
  if (NT > 1) stage(1);

  #pragma unroll
  for (int t = 0; t < NT; ++t) {
    // retire tile t's 4 loads; keep tile t+1's 4 in flight
    if (t + 1 < NT) { asm volatile("s_waitcnt vmcnt(4)" ::: "memory"); }
    else            { asm volatile("s_waitcnt vmcnt(0)" ::: "memory"); }
    __builtin_amdgcn_s_barrier();          // all waves' tile-t loads landed;
    __builtin_amdgcn_sched_barrier(0);     // all tile-(t-1) reads consumed
    if (t + 2 < NT) stage((t + 2) % 3);    // overwrites slot (t-1)%3

    const unsigned short* bp = &buf[t % 3][0];
    #pragma unroll
    for (int kk = 0; kk < 2; ++kk) {
      short8 af[2], bv[2];
      #pragma unroll
      for (int mi = 0; mi < 2; ++mi) af[mi] = *(const short8*)(bp + aoff[kk][mi]);
      #pragma unroll
      for (int ni = 0; ni < 2; ++ni) bv[ni] = *(const short8*)(bp + boff[kk][ni]);
      __builtin_amdgcn_s_setprio(1);
      #pragma unroll
      for (int mi = 0; mi < 2; ++mi)
        #pragma unroll
        for (int ni = 0; ni < 2; ++ni)
          acc[mi][ni] = __builtin_amdgcn_mfma_f32_16x16x32_bf16(af[mi], bv[ni], acc[mi][ni], 0, 0, 0);
      __builtin_amdgcn_s_setprio(0);
    }
  }
  // loop exit: vmcnt == 0, all LDS reads consumed.

  if (EPI == 0) {
    const unsigned short* ci = cinit + (long long)b * ciBatch;
    unsigned short* ob = outb + (long long)b * obBatch;
    #pragma unroll
    for (int mi = 0; mi < 2; ++mi)
      #pragma unroll
      for (int ni = 0; ni < 2; ++ni)
        #pragma unroll
        for (int j = 0; j < 4; ++j) {
          const int row = m0 + wr + mi * 16 + lhi * 4 + j;
          const int col = n0 + wc + ni * 16 + l15;
          ob[(long long)row * 1024 + col] =
              f2bf(acc[mi][ni][j] + bf2f(ci[(long long)row * 1024 + col]));
        }
  } else if (EPI == 2) {
    const unsigned short* ci = cinit + (long long)b * ciBatch;
    float* of = outf + (long long)b * ofBatch;
    #pragma unroll
    for (int mi = 0; mi < 2; ++mi)
      #pragma unroll
      for (int ni = 0; ni < 2; ++ni)
        #pragma unroll
        for (int j = 0; j < 4; ++j) {
          const int row = m0 + wr + mi * 16 + lhi * 4 + j;
          const int col = n0 + wc + ni * 16 + l15;
          of[(long long)row * 1024 + col] =
              acc[mi][ni][j] + bf2f(ci[(long long)row * 1024 + col]);
        }
  } else if (EPI == 3) {  // mix: logical M=512; chunk kc = row>>7
    #pragma unroll
    for (int mi = 0; mi < 2; ++mi)
      #pragma unroll
      for (int ni = 0; ni < 2; ++ni)
        #pragma unroll
        for (int j = 0; j < 4; ++j) {
          const int gr = m0 + wr + mi * 16 + lhi * 4 + j;   // 0..511
          const int kc = gr >> 7;
          const int rl = gr & 127;
          const int col = n0 + wc + ni * 16 + l15;
          unsigned short* dst = (kc == 3) ? (mixv + (long long)b * mvBatch)
                                          : (outb + (long long)b * obBatch + kc * (128 * 1024));
          float v = acc[mi][ni][j];
          if (kc == 0 && bias != nullptr) v += bias[rl];
          dst[(long long)rl * 1024 + col] = f2bf(v);
        }
  } else {  // EPI == 4: relu(+ci) -> transpose in LDS -> hnt[node][128]
    const unsigned short* ci = cinit + (long long)b * ciBatch;
    __syncthreads();   // all LDS reads consumed; vmcnt already 0
    unsigned short (*tt)[72] = (unsigned short(*)[72])(&buf[0][0]); // 9216B < slot0
    #pragma unroll
    for (int mi = 0; mi < 2; ++mi)
      #pragma unroll
      for (int ni = 0; ni < 2; ++ni)
        #pragma unroll
        for (int j = 0; j < 4; ++j) {
          const int rowl = wr + mi * 16 + lhi * 4 + j;      // local feat 0..63
          const int coll = wc + ni * 16 + l15;              // local node 0..63
          float v = acc[mi][ni][j] +
                    bf2f(ci[(long long)(m0 + rowl) * 1024 + n0 + coll]);
          tt[coll][rowl] = f2bf(fmaxf(v, 0.f));
        }
    __syncthreads();
    unsigned short* ob = outb + (long long)b * obBatch;     // hnt, stride 128
    #pragma unroll
    for (int i = 0; i < 2; ++i) {
      const int flat = tid + i * 256;     // 0..511 = 64 nodes x 8 segs
      const int node = flat >> 3;
      const int seg  = flat & 7;
      *(short8*)(&ob[(long long)(n0 + node) * 128 + m0 + seg * 8]) =
          *(const short8*)(&tt[node][seg * 8]);
    }
  }
}

// ---------------------------------------------------------------------------
// prep_all: one kernel, 512 blocks, batch-clustered (proven).
//  (a) weight pack W1/W2/biasAB  (b) S -> S^T bf16  (c) [x;h] -> z0t bf16
// ---------------------------------------------------------------------------
__global__ __launch_bounds__(256)
void prep_all(const float* __restrict__ x, const float* __restrict__ hid,
              const float* __restrict__ S,
              const float* __restrict__ wA, const float* __restrict__ wB,
              const float* __restrict__ wD,
              const float* __restrict__ bA, const float* __restrict__ bB,
              unsigned short* __restrict__ St, unsigned short* __restrict__ z0t,
              unsigned short* __restrict__ W1, unsigned short* __restrict__ W2,
              float* __restrict__ biasAB)
{
  __shared__ float t[64][65];
  const int wg  = blockIdx.x;          // 0..511
  const int tid = threadIdx.x;

  // ---- weight pack: 196736 elems over 512 blocks x 512 ----
  #pragma unroll
  for (int k = 0; k < 2; ++k) {
    const int i = wg * 512 + k * 256 + tid;
    if (i < 512 * 256) {
      const int row = i >> 8, g2 = i & 255;
      const int kk = row >> 7, h = row & 127;
      const float v = (g2 < 128) ? wA[(h * 4 + kk) * 128 + g2]
                                 : wB[(h * 4 + kk) * 128 + (g2 - 128)];
      W1[i] = f2bf(v);
    } else if (i < 512 * 256 + 512 * 128) {
      const int j = i - 512 * 256;
      const int row = j >> 7, h2 = j & 127;
      const int kk = row >> 7, f = row & 127;
      W2[j] = f2bf(wD[(f * 4 + kk) * 128 + h2]);
    } else if (i < 512 * 256 + 512 * 128 + 128) {
      const int l = i - 512 * 256 - 512 * 128;
      biasAB[l] = bA[l] + bB[l];
    }
  }

  // batch-cluster mapping: 32 blocks per batch, batch pinned to XCD pair
  const int b  = (wg & 7) * 2 + (wg >> 3) / 32;
  const int jj = (wg >> 3) % 32;       // 0..31 within batch
  const int tx = tid & 63;
  const int ty = tid >> 6;             // 0..3

  // ---- S^T: 8 of the 256 64x64 tiles of this batch ----
  const float* Sb = S + (long long)b * (1024 * 1024);
  unsigned short* Stb = St + (long long)b * (1024 * 1024);
  for (int q = 0; q < 8; ++q) {
    const int tile = jj * 8 + q;               // 0..255
    const int c0 = (tile & 15) * 64, r0 = (tile >> 4) * 64;
    __syncthreads();
    #pragma unroll
    for (int i = 0; i < 64; i += 4)
      t[ty + i][tx] = Sb[(long long)(r0 + ty + i) * 1024 + c0 + tx];
    __syncthreads();
    #pragma unroll
    for (int i = 0; i < 64; i += 4)
      Stb[(long long)(c0 + ty + i) * 1024 + r0 + tx] = f2bf(t[tx][ty + i]);
  }

  // ---- [x;h]^T: 2 of the 64 tiles of this batch ----
  unsigned short* zb = z0t + (long long)b * (1024 * 256);
  for (int q = 0; q < 2; ++q) {
    const int idx2 = jj * 2 + q;               // 0..63
    const int srch = idx2 >> 5;                // 0: x, 1: hidden
    const int t2   = idx2 & 31;
    const int c0 = (t2 & 15) * 64, r0 = ((t2 >> 4) & 1) * 64;
    const float* sp = (srch ? hid : x) + (long long)b * (128 * 1024);
    __syncthreads();
    #pragma unroll
    for (int i = 0; i < 64; i += 4)
      t[ty + i][tx] = sp[(long long)(r0 + ty + i) * 1024 + c0 + tx];
    __syncthreads();
    #pragma unroll
    for (int i = 0; i < 64; i += 4)
      zb[(long long)(c0 + ty + i) * 256 + srch * 128 + r0 + tx] = f2bf(t[tx][ty + i]);
  }
}

// ---------------------------------------------------------------------------
extern "C" void kernel_launch(void* const* d_in, const int* in_sizes, int n_in,
                              void* d_out, int out_size, void* d_ws, size_t ws_size,
                              hipStream_t stream)
{
  const float* x   = (const float*)d_in[0];
  const float* hid = (const float*)d_in[1];
  const float* S   = (const float*)d_in[2];
  const float* wA  = (const float*)d_in[3];
  const float* wB  = (const float*)d_in[4];
  const float* wD  = (const float*)d_in[5];
  const float* bA  = (const float*)d_in[6];
  const float* bB  = (const float*)d_in[7];
  const float* bD  = (const float*)d_in[8];
  float* out = (float*)d_out;

  char* ws = (char*)d_ws;
  auto alloc = [&](size_t bytes) {
    char* p = ws;
    ws += (bytes + 255) & ~(size_t)255;
    return p;
  };
  unsigned short* St   = (unsigned short*)alloc(16ull * 1024 * 1024 * 2); // S^T bf16
  unsigned short* z0t  = (unsigned short*)alloc(16ull * 1024 * 256 * 2);  // [x;h]^T bf16
  unsigned short* cini = (unsigned short*)alloc(16ull * 3 * 128 * 1024 * 2); // w_0..2 / d_0..2
  unsigned short* vb0  = (unsigned short*)alloc(16ull * 128 * 1024 * 2);
  unsigned short* vb1  = (unsigned short*)alloc(16ull * 128 * 1024 * 2);
  unsigned short* hnt  = (unsigned short*)alloc(16ull * 1024 * 128 * 2);  // h_next^T (node-major)
  unsigned short* W1   = (unsigned short*)alloc(512 * 256 * 2);
  unsigned short* W2   = (unsigned short*)alloc(512 * 128 * 2);
  float*          bAB  = (float*)alloc(128 * 4);

  const long long NB  = 128 * 1024;    // per-batch [128][1024]
  const long long NB2 = 1024 * 128;    // per-batch [1024][128]
  const long long CI  = 3 * NB;        // cinit batch stride
  const long long SB  = 1024 * 1024;   // S batch stride

  prep_all<<<dim3(512), 256, 0, stream>>>(x, hid, S, wA, wB, wD, bA, bB,
                                          St, z0t, W1, W2, bAB);

  // mix1: w_k = [A_k|B_k] @ [x;h]  (k=3 -> vb0, k<3 -> cini, k=0 += bA+bB)
  gemm_bt<3, 256><<<dim3(2048), 256, 0, stream>>>(W1, 0, 256, z0t, 1024 * 256, 256,
      nullptr, 0, bAB, cini, CI, nullptr, 0, vb0, NB);
  // Horner phase 1: v = ((w3 S + w2) S + w1) S + w0 ; h_next^T = relu(...)^T
  gemm_bt<0, 1024><<<dim3(512), 256, 0, stream>>>(vb0, NB, 1024, St, SB, 1024,
      cini + 2 * NB, CI, nullptr, vb1, NB, nullptr, 0, nullptr, 0);
  gemm_bt<0, 1024><<<dim3(512), 256, 0, stream>>>(vb1, NB, 1024, St, SB, 1024,
      cini + 1 * NB, CI, nullptr, vb0, NB, nullptr, 0, nullptr, 0);
  gemm_bt<4, 1024><<<dim3(512), 256, 0, stream>>>(vb0, NB, 1024, St, SB, 1024,
      cini, CI, nullptr, hnt, NB2, nullptr, 0, nullptr, 0);

  // mix2: d_k = D_k @ h_next  (k=3 -> vb0, k<3 -> cini, k=0 += bD)
  gemm_bt<3, 128><<<dim3(2048), 256, 0, stream>>>(W2, 0, 128, hnt, NB2, 128,
      nullptr, 0, bD, cini, CI, nullptr, 0, vb0, NB);
  // Horner phase 2: out = ((d3 S + d2) S + d1) S + d0
  gemm_bt<0, 1024><<<dim3(512), 256, 0, stream>>>(vb0, NB, 1024, St, SB, 1024,
      cini + 2 * NB, CI, nullptr, vb1, NB, nullptr, 0, nullptr, 0);
  gemm_bt<0, 1024><<<dim3(512), 256, 0, stream>>>(vb1, NB, 1024, St, SB, 1024,
      cini + 1 * NB, CI, nullptr, vb0, NB, nullptr, 0, nullptr, 0);
  gemm_bt<2, 1024><<<dim3(512), 256, 0, stream>>>(vb0, NB, 1024, St, SB, 1024,
      cini, CI, nullptr, nullptr, 0, out, NB, nullptr, 0);
}